// Round 1
// 151.225 us; speedup vs baseline: 1.0152x; 1.0152x over previous
//
#include <hip/hip_runtime.h>
#include <math.h>

// Problem: [16,1,1024,1024] fp32 pred/target -> scalar weighted mean-abs curvature loss.
// R8: software-pipeline the row loads. R7 (this file's parent) had zero
// load-to-use distance: prep(y+2) loaded 6 dwords and combine+curv_pair consumed
// them immediately -> s_waitcnt vmcnt(0) every iteration, VALUBusy 62%,
// occupancy 34% despite VGPR=64. Memory throughput is NOT the limit (87.5 MB
// HBM ~ 14 us; L2/L1 far under budget); VALU floor ~26 us; 58 us measured =
// latency-bound. Fix: split prep into ldrow (issue raw loads) / combine
// (window math); issue row i+2's loads BEFORE waiting on row i+1's and before
// curv_pair(i). One curv_pair (~250 issue cyc) of cover per load batch.
// Costs ~6-12 VGPR (8 -> 6-7 waves/SIMD cap; effective occupancy was ~2.7 so
// the trade is latency-tolerance-positive).
// Numerics = R7 exactly (absmax 0.0): same ops, same order, same EPS handling.

constexpr int IMG_B = 16;
constexpr int IMG_H = 1024;
constexpr int IMG_W = 1024;
constexpr int ROWS  = 16;                      // rows per block
constexpr int BLOCK = 256;                     // 256 threads = 256 columns
constexpr int TILES_X = IMG_W / BLOCK;         // 4
constexpr int TILES_Y = IMG_H / ROWS;          // 64
constexpr int NBLOCKS = IMG_B * TILES_Y * TILES_X;  // 4096
constexpr float EPS = 1e-8f;

// scale constants: p = gx/80, q = gy/80, r = rxx/300, 2s = sxy/200, t = tyy/300
constexpr float A2 = 1.0f / 6400.0f;
constexpr float Bc = 1.0f / 300.0f;
constexpr float C2 = 1.0f / 200.0f;

typedef float f2v __attribute__((ext_vector_type(2)));

__device__ __forceinline__ f2v pk_fma(f2v a, f2v b, f2v c) {
    return __builtin_elementwise_fma(a, b, c);
}

// rolling-window row state, lanes = {pred, target}
struct Rowv { f2v hx, hs, rs; };
// raw 3-tap row load, lanes = {pred, target}
struct Raw  { f2v t0, t1, t2; };

// prof/plan true scale; mean2 = 2*mean (weight absorbs the 1/2). Lane-parallel
// over {pred, target}; transcendentals + flat-mask stay per-component.
__device__ __forceinline__ void curv_pair(const Rowv& a, const Rowv& b, const Rowv& c,
                                          f2v& prof, f2v& plan, f2v& mean2)
{
    const f2v A2f = {A2, A2}, Bcf = {Bc, Bc}, C2f = {C2, C2};
    const f2v m3  = {-3.0f, -3.0f}, two = {2.0f, 2.0f};
    const f2v epsf = {EPS, EPS};

    const f2v gx  = pk_fma(two, b.hx, a.hx + c.hx);   // sobel_x (raw)
    const f2v gy  = c.hs - a.hs;                      // sobel_y (raw)
    const f2v tot = (a.rs + c.rs) + b.rs;             // 3x3 sum
    const f2v H   = (a.hs + c.hs) + b.hs;
    const f2v rxx = pk_fma(m3, H - tot, tot);         // k_xx * 3 (raw)
    const f2v tyy = pk_fma(m3, b.rs, tot);            // k_yy * 3 (raw)
    const f2v sxy = a.hx - c.hx;                      // k_xy * 4 (raw)

    const f2v gx2 = gx * gx, gy2 = gy * gy, gxgy = gx * gy;
    const f2v g2  = gx2 + gy2;
    const f2v d1  = A2f * g2;                         // p^2 + q^2
    const f2v od  = d1 + f2v{1.0f, 1.0f};

    f2v rsq_od, sq_d1;                                // per-component transcendentals
    rsq_od.x = __builtin_amdgcn_rsqf(od.x);
    rsq_od.y = __builtin_amdgcn_rsqf(od.y);
    sq_d1.x  = __builtin_amdgcn_sqrtf(d1.x);
    sq_d1.y  = __builtin_amdgcn_sqrtf(d1.y);
    const f2v sq_od = od * rsq_od;                    // sqrt(1+d1)

    const f2v h1    = pk_fma(tyy, gy2, rxx * gx2);
    const f2v h3    = pk_fma(tyy, gx2, rxx * gy2);
    const f2v h2c   = C2f * (sxy * gxgy);
    const f2v nprof = A2f * pk_fma(Bcf, h1,  h2c);    // r*p2+2s*pq+t*q2
    const f2v nplan = A2f * pk_fma(Bcf, h3, -h2c);    // r*q2-2s*pq+t*p2
    const f2v mnum  = pk_fma(Bcf, rxx + tyy, nplan);  // (1+q2)r-2pq*s+(1+p2)t

    const f2v den_p = pk_fma(d1, sq_od, epsf);        // d1*sqrt(1+d1)+EPS
    const f2v den_l = pk_fma(d1, sq_d1, epsf);        // d1^1.5+EPS
    const f2v plprod = den_p * den_l;                 // >=1e-16, no underflow
    f2v rcpPL;
    rcpPL.x = __builtin_amdgcn_rcpf(plprod.x);
    rcpPL.y = __builtin_amdgcn_rcpf(plprod.y);

    prof  = (nprof * den_l) * rcpPL;
    plan  = (nplan * den_p) * rcpPL;
    mean2 = mnum * ((rsq_od * rsq_od) * rsq_od);      // mnum/od^1.5 = 2*mean
    // flat mask per component
    prof.x = (d1.x < EPS) ? 0.0f : prof.x;
    prof.y = (d1.y < EPS) ? 0.0f : prof.y;
    plan.x = (d1.x < EPS) ? 0.0f : plan.x;
    plan.y = (d1.y < EPS) ? 0.0f : plan.y;
}

__global__ __launch_bounds__(BLOCK) void curv_loss_main(
    const float* __restrict__ pred, const float* __restrict__ targ,
    float* __restrict__ blocksums)
{
    const int tid = threadIdx.x;
    const int b   = blockIdx.x;
    const int tx  = b & (TILES_X - 1);
    const int ty  = (b >> 2) & (TILES_Y - 1);
    const int img = b >> 8;                   // 4*64 = 256 blocks per image
    const int y0  = ty * ROWS;
    const int x   = tx * BLOCK + tid;

    const size_t ibase = (size_t)img * (size_t)(IMG_H * IMG_W);
    const char* __restrict__ Pc = (const char*)(pred + ibase);
    const char* __restrict__ Tc = (const char*)(targ + ibase);

    const bool xm = (x > 0);
    const bool xp = (x < IMG_W - 1);
    // per-tap byte offsets within a row (clamped at image edge; value masked to 0)
    const int eL = (x + (xm ? -1 : 0)) << 2;
    const int eC = x << 2;
    const int eR = (x + (xp ? +1 : 0)) << 2;

    // issue the 6 raw tap loads for row y (no combine -> no vmcnt wait here)
    auto ldrow = [&](int y, Raw& r) {
        if ((unsigned)y < (unsigned)IMG_H) {          // block-uniform branch
            const int vo = y << 12;
            r.t0.x = *(const float*)(Pc + vo + eL);
            r.t0.y = *(const float*)(Tc + vo + eL);
            r.t1.x = *(const float*)(Pc + vo + eC);
            r.t1.y = *(const float*)(Tc + vo + eC);
            r.t2.x = *(const float*)(Pc + vo + eR);
            r.t2.y = *(const float*)(Tc + vo + eR);
        } else {                                       // zero 'SAME' padding row
            r.t0 = f2v{0.0f, 0.0f}; r.t1 = f2v{0.0f, 0.0f}; r.t2 = f2v{0.0f, 0.0f};
        }
    };

    // window combos (consumes the raw loads -> the vmcnt wait lands here)
    auto combine = [&](const Raw& r, Rowv& o) {
        f2v w0 = r.t0, w2 = r.t2;
        const f2v w1 = r.t1;
        w0.x = xm ? w0.x : 0.0f;  w0.y = xm ? w0.y : 0.0f;
        w2.x = xp ? w2.x : 0.0f;  w2.y = xp ? w2.y : 0.0f;
        const f2v e = w0 + w2;
        o.hx = w2 - w0;
        o.hs = pk_fma(f2v{2.0f, 2.0f}, w1, e);
        o.rs = e + w1;
    };

    Rowv w[3];
    Raw  r;
    ldrow(y0 - 1, r); combine(r, w[0]);
    ldrow(y0,     r); combine(r, w[1]);
    ldrow(y0 + 1, r);                 // stays in flight across loop entry

    float acc = 0.0f;
#pragma unroll
    for (int i = 0; i < ROWS; ++i) {
        const int ia = i % 3, ib = (i + 1) % 3, ic = (i + 2) % 3;
        // 1) prefetch row i+2 FIRST (independent of r; keeps it in flight
        //    past the vmcnt wait that combine() is about to take)
        Raw rn;
        if (i < ROWS - 1) {
            ldrow(y0 + i + 2, rn);
        } else {
            rn.t0 = f2v{0.0f, 0.0f}; rn.t1 = f2v{0.0f, 0.0f}; rn.t2 = f2v{0.0f, 0.0f};
        }
        // 2) now consume the loads issued one iteration ago
        combine(r, w[ic]);
        // 3) full curvature body covers the latency of rn's loads
        f2v prof, plan, mean2;
        curv_pair(w[ia], w[ib], w[ic], prof, plan, mean2);
        acc = fmaf(0.5f, fabsf(prof.x  - prof.y),  acc);
        acc = fmaf(0.3f, fabsf(plan.x  - plan.y),  acc);
        acc = fmaf(0.1f, fabsf(mean2.x - mean2.y), acc);  // 0.2*|dMean|
        r = rn;   // SSA-renamed away under full unroll
    }

    // wave64 reduce, then cross-wave via LDS
#pragma unroll
    for (int off = 32; off > 0; off >>= 1) acc += __shfl_down(acc, off, 64);
    __shared__ float ws[BLOCK / 64];
    const int lane = tid & 63, wid = tid >> 6;
    if (lane == 0) ws[wid] = acc;
    __syncthreads();
    if (tid == 0)
        blocksums[b] = (ws[0] + ws[1]) + (ws[2] + ws[3]);
}

__global__ __launch_bounds__(BLOCK) void curv_loss_final(
    const float* __restrict__ blocksums, float* __restrict__ out)
{
    const int tid = threadIdx.x;
    float v = 0.0f;
#pragma unroll
    for (int i = 0; i < NBLOCKS / BLOCK; ++i) v += blocksums[i * BLOCK + tid];
#pragma unroll
    for (int off = 32; off > 0; off >>= 1) v += __shfl_down(v, off, 64);
    __shared__ float ws[BLOCK / 64];
    const int lane = tid & 63, wid = tid >> 6;
    if (lane == 0) ws[wid] = v;
    __syncthreads();
    if (tid == 0) {
        const float tot = (ws[0] + ws[1]) + (ws[2] + ws[3]);
        out[0] = tot * (1.0f / (float)(IMG_B * IMG_H * IMG_W));
    }
}

extern "C" void kernel_launch(void* const* d_in, const int* in_sizes, int n_in,
                              void* d_out, int out_size, void* d_ws, size_t ws_size,
                              hipStream_t stream)
{
    const float* pred = (const float*)d_in[0];
    const float* targ = (const float*)d_in[1];
    float* out = (float*)d_out;
    float* blocksums = (float*)d_ws;   // 4096 floats; every slot written each call

    curv_loss_main<<<NBLOCKS, BLOCK, 0, stream>>>(pred, targ, blocksums);
    curv_loss_final<<<1, BLOCK, 0, stream>>>(blocksums, out);
}